// Round 1
// baseline (1527.076 us; speedup 1.0000x reference)
//
#include <hip/hip_runtime.h>
#include <math.h>

#define NROWS 262144
#define NC    1000
#define SCALEF 1.0f

// ---- workspace layout (bytes) ----
// [0, 4000000)                     float cm[NC*NC]
// [4000000, 4000000+4*NROWS)       float glp[NROWS]
// [+4*NROWS, +8*NROWS)             int   pair[NROWS]   (t*NC + p)
// [WS_SCAL, WS_SCAL+8)             double losssum
// [WS_SCAL+8, +12)                 unsigned maxbits
#define WS_GLP_OFF   4000000
#define WS_PAIR_OFF  (4000000 + NROWS * 4)
#define WS_SCAL_OFF  (4000000 + NROWS * 8)   // 6097152, 8-aligned

__global__ __launch_bounds__(256) void k_init(const float* __restrict__ cost_in,
                                              float* __restrict__ cm,
                                              double* __restrict__ losssum,
                                              unsigned* __restrict__ maxbits) {
    int i = blockIdx.x * 256 + threadIdx.x;
    if (i < NC * NC) cm[i] = cost_in[i];
    if (i == 0) { *losssum = 0.0; *maxbits = 0u; }
}

// One wave (64 lanes) per row. Each lane loads 4 float4 = 16 elems.
// Element e of a row lives at: j = e>>8, lane = (e&255)>>2, m = e&3.
__global__ __launch_bounds__(256) void k_row(const float* __restrict__ outs,
                                             const int* __restrict__ targets,
                                             float* __restrict__ cm,
                                             float* __restrict__ glp,
                                             int* __restrict__ pair) {
    int row  = blockIdx.x * 4 + (threadIdx.x >> 6);
    int lane = threadIdx.x & 63;
    if (row >= NROWS) return;

    const float* rp = outs + (size_t)row * NC;
    int t = targets[row];
    float tval = rp[t];                 // likely L1 hit after vector loads below

    float4 f0 = *(const float4*)(rp + 4 * lane);
    float4 f1 = *(const float4*)(rp + 256 + 4 * lane);
    float4 f2 = *(const float4*)(rp + 512 + 4 * lane);
    float4 f3;
    bool has3 = (4 * lane) < (NC - 768);   // 4*lane < 232
    if (has3) f3 = *(const float4*)(rp + 768 + 4 * lane);
    else      f3 = make_float4(-INFINITY, -INFINITY, -INFINITY, -INFINITY);

    float v[16] = {f0.x, f0.y, f0.z, f0.w,
                   f1.x, f1.y, f1.z, f1.w,
                   f2.x, f2.y, f2.z, f2.w,
                   f3.x, f3.y, f3.z, f3.w};

    // per-lane max + argmax (first occurrence)
    float mx = -INFINITY;
    int   ami = 0x7fffffff;
    #pragma unroll
    for (int q = 0; q < 16; ++q) {
        int idx = 256 * (q >> 2) + 4 * lane + (q & 3);
        float val = v[q];
        if (val > mx || (val == mx && idx < ami)) { mx = val; ami = idx; }
    }
    // wave reduce (64 lanes), tie-break lowest index
    #pragma unroll
    for (int off = 32; off; off >>= 1) {
        float omx = __shfl_xor(mx, off, 64);
        int   oi  = __shfl_xor(ami, off, 64);
        if (omx > mx || (omx == mx && oi < ami)) { mx = omx; ami = oi; }
    }

    // sum of exp(x - mx); invalid entries are -inf -> exp = 0
    float s = 0.f;
    #pragma unroll
    for (int q = 0; q < 16; ++q) s += __expf(v[q] - mx);
    #pragma unroll
    for (int off = 32; off; off >>= 1) s += __shfl_xor(s, off, 64);

    if (lane == 0) {
        float lp_t = tval - mx - __logf(s);   // log_softmax at target
        glp[row]  = lp_t;
        pair[row] = t * NC + ami;
        atomicAdd(&cm[t * NC + ami], 1.0f);
    }
}

__global__ __launch_bounds__(256) void k_cmmax(const float* __restrict__ cm,
                                               unsigned* __restrict__ maxbits) {
    int idx = blockIdx.x * 256 + threadIdx.x;
    float val = 0.f;
    if (idx < NC * NC) {
        int r = idx / NC;
        int c = idx - r * NC;
        val = (r == c) ? 0.f : cm[idx];   // diagonal zeroed (not written back;
                                          // loss kernel handles t==p analytically)
    }
    #pragma unroll
    for (int off = 32; off; off >>= 1) val = fmaxf(val, __shfl_xor(val, off, 64));
    if ((threadIdx.x & 63) == 0)
        atomicMax(maxbits, __float_as_uint(val));  // all values >= 0
}

__global__ __launch_bounds__(256) void k_loss(const float* __restrict__ cm,
                                              const float* __restrict__ glp,
                                              const int* __restrict__ pair,
                                              const unsigned* __restrict__ maxbits,
                                              double* __restrict__ losssum) {
    int n = blockIdx.x * 256 + threadIdx.x;
    double part = 0.0;
    if (n < NROWS) {
        int pr = pair[n];
        int t = pr / NC;
        int p = pr - t * NC;
        float cost;
        if (t == p) cost = 1.0f;   // zeroed diagonal: 0/max*SCALE + 1
        else        cost = cm[pr] / __uint_as_float(*maxbits) * SCALEF + 1.0f;
        part = (double)glp[n] * (double)cost;
    }
    #pragma unroll
    for (int off = 32; off; off >>= 1) part += __shfl_xor(part, off, 64);
    if ((threadIdx.x & 63) == 0) atomicAdd(losssum, part);
}

__global__ void k_final(const double* __restrict__ losssum, float* __restrict__ out) {
    out[0] = (float)(-(*losssum) / (double)NROWS);
}

extern "C" void kernel_launch(void* const* d_in, const int* in_sizes, int n_in,
                              void* d_out, int out_size, void* d_ws, size_t ws_size,
                              hipStream_t stream) {
    const float* outs    = (const float*)d_in[0];
    const float* cost_in = (const float*)d_in[1];
    const int*   targets = (const int*)d_in[2];

    char* ws = (char*)d_ws;
    float*    cm      = (float*)ws;
    float*    glp     = (float*)(ws + WS_GLP_OFF);
    int*      pair    = (int*)(ws + WS_PAIR_OFF);
    double*   losssum = (double*)(ws + WS_SCAL_OFF);
    unsigned* maxbits = (unsigned*)(ws + WS_SCAL_OFF + 8);

    k_init<<<(NC * NC + 255) / 256, 256, 0, stream>>>(cost_in, cm, losssum, maxbits);
    k_row<<<NROWS / 4, 256, 0, stream>>>(outs, targets, cm, glp, pair);
    k_cmmax<<<(NC * NC + 255) / 256, 256, 0, stream>>>(cm, maxbits);
    k_loss<<<(NROWS + 255) / 256, 256, 0, stream>>>(cm, glp, pair, maxbits, losssum);
    k_final<<<1, 1, 0, stream>>>(losssum, (float*)d_out);
}

// Round 2
// 1338.814 us; speedup vs baseline: 1.1406x; 1.1406x over previous
//
#include <hip/hip_runtime.h>
#include <math.h>

#define NROWS 262144
#define NC    1000
#define NCELL (NC * NC)
#define SCALEF 1.0f

// ---- workspace layout (bytes) ----
// [0, 4e6)        float cm[NC*NC]      counts (+cost_matrix input)
// [4e6, 8e6)      float S[NC*NC]       sum of glp per (t,p) cell
// [8e6, +8)       double losssum
// [8e6+8, +4)     unsigned maxbits
// [8e6+12, +4)    unsigned done counter
#define WS_S_OFF    4000000
#define WS_SCAL_OFF 8000000

__global__ __launch_bounds__(256) void k_init(const float* __restrict__ cost_in,
                                              float* __restrict__ cm,
                                              float* __restrict__ S,
                                              double* __restrict__ losssum,
                                              unsigned* __restrict__ scal) {
    int i = blockIdx.x * 256 + threadIdx.x;
    if (i < NCELL) { cm[i] = cost_in[i]; S[i] = 0.f; }
    if (i == 0) { *losssum = 0.0; scal[0] = 0u; scal[1] = 0u; }
}

// One wave (64 lanes) per row; each lane holds 16 elements (4x float4).
// Element e of a row: segment q = e>>8, lane = (e&255)>>2, sub = e&3.
__global__ __launch_bounds__(256) void k_row(const float* __restrict__ outs,
                                             const int* __restrict__ targets,
                                             float* __restrict__ cm,
                                             float* __restrict__ S) {
    int row  = blockIdx.x * 4 + (threadIdx.x >> 6);
    int lane = threadIdx.x & 63;

    const float* rp = outs + (size_t)row * NC;
    int t = targets[row];

    float4 f0 = *(const float4*)(rp + 4 * lane);
    float4 f1 = *(const float4*)(rp + 256 + 4 * lane);
    float4 f2 = *(const float4*)(rp + 512 + 4 * lane);
    float4 f3;
    bool has3 = (4 * lane) < (NC - 768);   // 4*lane < 232
    if (has3) f3 = *(const float4*)(rp + 768 + 4 * lane);
    else      f3 = make_float4(-INFINITY, -INFINITY, -INFINITY, -INFINITY);

    float tval = rp[t];                    // after vector loads: L1 hit

    float v[16] = {f0.x, f0.y, f0.z, f0.w,
                   f1.x, f1.y, f1.z, f1.w,
                   f2.x, f2.y, f2.z, f2.w,
                   f3.x, f3.y, f3.z, f3.w};

    // per-lane max + argmax (first occurrence wins ties)
    float mx = -INFINITY;
    int   ami = 0x7fffffff;
    #pragma unroll
    for (int q = 0; q < 16; ++q) {
        int idx = 256 * (q >> 2) + 4 * lane + (q & 3);
        float val = v[q];
        if (val > mx || (val == mx && idx < ami)) { mx = val; ami = idx; }
    }
    #pragma unroll
    for (int off = 32; off; off >>= 1) {
        float omx = __shfl_xor(mx, off, 64);
        int   oi  = __shfl_xor(ami, off, 64);
        if (omx > mx || (omx == mx && oi < ami)) { mx = omx; ami = oi; }
    }

    // sum of exp(x - mx); -inf pad entries contribute 0
    float s = 0.f;
    #pragma unroll
    for (int q = 0; q < 16; ++q) s += __expf(v[q] - mx);
    #pragma unroll
    for (int off = 32; off; off >>= 1) s += __shfl_xor(s, off, 64);

    if (lane == 0) {
        float lp_t = tval - mx - __logf(s);   // log_softmax at target
        int cell = t * NC + ami;
        atomicAdd(&cm[cell], 1.0f);           // confusion count
        atomicAdd(&S[cell], lp_t);            // glp sum per (t,p)
    }
}

__global__ __launch_bounds__(256) void k_cmmax(const float* __restrict__ cm,
                                               unsigned* __restrict__ maxbits) {
    __shared__ float red[4];
    float val = 0.f;
    for (int idx = blockIdx.x * 256 + threadIdx.x; idx < NCELL; idx += gridDim.x * 256) {
        int r = idx / NC;
        int c = idx - r * NC;
        float x = (r == c) ? 0.f : cm[idx];   // zero diagonal on the fly
        val = fmaxf(val, x);
    }
    #pragma unroll
    for (int off = 32; off; off >>= 1) val = fmaxf(val, __shfl_xor(val, off, 64));
    if ((threadIdx.x & 63) == 0) red[threadIdx.x >> 6] = val;
    __syncthreads();
    if (threadIdx.x == 0) {
        val = fmaxf(fmaxf(red[0], red[1]), fmaxf(red[2], red[3]));
        atomicMax(maxbits, __float_as_uint(val));   // counts >= 0, uint-order ok
    }
}

// loss_sum = sum over cells of S[i] * (1 + [r!=c] * cm[i]/mx); last block finalizes.
__global__ __launch_bounds__(256) void k_loss(const float* __restrict__ cm,
                                              const float* __restrict__ S,
                                              const unsigned* __restrict__ maxbits,
                                              double* __restrict__ losssum,
                                              unsigned* __restrict__ counter,
                                              float* __restrict__ out) {
    __shared__ double red[4];
    float inv_mx = SCALEF / __uint_as_float(*maxbits);
    double part = 0.0;
    for (int idx = blockIdx.x * 256 + threadIdx.x; idx < NCELL; idx += gridDim.x * 256) {
        int r = idx / NC;
        int c = idx - r * NC;
        float sv = S[idx];
        float cost = (r == c) ? 1.0f : fmaf(cm[idx], inv_mx, 1.0f);
        part += (double)(sv * cost);
    }
    #pragma unroll
    for (int off = 32; off; off >>= 1) part += __shfl_xor(part, off, 64);
    if ((threadIdx.x & 63) == 0) red[threadIdx.x >> 6] = part;
    __syncthreads();
    if (threadIdx.x == 0) {
        part = red[0] + red[1] + red[2] + red[3];
        atomicAdd(losssum, part);
        __threadfence();
        unsigned prev = atomicAdd(counter, 1u);
        if (prev == gridDim.x - 1) {
            double total = atomicAdd(losssum, 0.0);  // coherent read-back
            out[0] = (float)(-total / (double)NROWS);
        }
    }
}

extern "C" void kernel_launch(void* const* d_in, const int* in_sizes, int n_in,
                              void* d_out, int out_size, void* d_ws, size_t ws_size,
                              hipStream_t stream) {
    const float* outs    = (const float*)d_in[0];
    const float* cost_in = (const float*)d_in[1];
    const int*   targets = (const int*)d_in[2];

    char* ws = (char*)d_ws;
    float*    cm      = (float*)ws;
    float*    S       = (float*)(ws + WS_S_OFF);
    double*   losssum = (double*)(ws + WS_SCAL_OFF);
    unsigned* maxbits = (unsigned*)(ws + WS_SCAL_OFF + 8);
    unsigned* counter = (unsigned*)(ws + WS_SCAL_OFF + 12);

    k_init<<<(NCELL + 255) / 256, 256, 0, stream>>>(cost_in, cm, S, losssum, maxbits);
    k_row<<<NROWS / 4, 256, 0, stream>>>(outs, targets, cm, S);
    k_cmmax<<<512, 256, 0, stream>>>(cm, maxbits);
    k_loss<<<512, 256, 0, stream>>>(cm, S, maxbits, losssum, counter, (float*)d_out);
}